// Round 1
// baseline (126.794 us; speedup 1.0000x reference)
//
#include <hip/hip_runtime.h>

#define BATCH 4
#define SEQ   4096
#define EMB   1024
#define HD    64
#define NROW  (BATCH*SEQ)

typedef float f32x4  __attribute__((ext_vector_type(4)));
typedef short bf16x8 __attribute__((ext_vector_type(8)));

#define LOG2E 1.4426950408889634f

static __device__ __forceinline__ short f2bf(float f) {
  union { float f; unsigned u; } v; v.f = f;
  unsigned r = v.u + 0x7fffu + ((v.u >> 16) & 1u);
  return (short)(r >> 16);
}

// ---------------------------------------------------------------------------
// Wt[n][e] = W_{n/64}[e][n%64] as bf16, n in [0,192). B-fragment friendly.
// ---------------------------------------------------------------------------
__global__ void wt_kernel(const float* __restrict__ Wq, const float* __restrict__ Wk,
                          const float* __restrict__ Wv, short* __restrict__ Wt) {
  int n = blockIdx.x;
  const float* W = (n < 64) ? Wq : (n < 128) ? Wk : Wv;
  int h = n & 63;
  for (int e = threadIdx.x; e < EMB; e += blockDim.x)
    Wt[(size_t)n * EMB + e] = f2bf(W[(size_t)e * HD + h]);
}

// ---------------------------------------------------------------------------
// QKV projection: [16384 x 1024] x [1024 x 192] via mfma_f32_16x16x32_bf16.
// Block = 256 threads (4 waves x 16 rows). Writes Qb,Kb row-major bf16 and
// Vt transposed [B][64][S] bf16.
// ---------------------------------------------------------------------------
__global__ __launch_bounds__(256) void qkv_kernel(
    const float* __restrict__ X, const short* __restrict__ Wt,
    const float* __restrict__ bq, const float* __restrict__ bk, const float* __restrict__ bv,
    short* __restrict__ Qb, short* __restrict__ Kb, short* __restrict__ Vt) {
  int tid  = threadIdx.x;
  int w    = tid >> 6;
  int lane = tid & 63;
  int g    = lane >> 4;   // k-group
  int mi   = lane & 15;   // m index within 16
  int rowA = blockIdx.x * 64 + w * 16 + mi;
  const float* xrow = X + (size_t)rowA * EMB;

  f32x4 acc[12];
#pragma unroll
  for (int i = 0; i < 12; ++i) acc[i] = (f32x4){0.f, 0.f, 0.f, 0.f};

  for (int k0 = 0; k0 < EMB; k0 += 32) {
    float4 xa = *(const float4*)(xrow + k0 + 8 * g);
    float4 xb = *(const float4*)(xrow + k0 + 8 * g + 4);
    bf16x8 af;
    af[0] = f2bf(xa.x); af[1] = f2bf(xa.y); af[2] = f2bf(xa.z); af[3] = f2bf(xa.w);
    af[4] = f2bf(xb.x); af[5] = f2bf(xb.y); af[6] = f2bf(xb.z); af[7] = f2bf(xb.w);
#pragma unroll
    for (int ct = 0; ct < 12; ++ct) {
      bf16x8 bfr = *(const bf16x8*)(Wt + (size_t)(ct * 16 + mi) * EMB + k0 + 8 * g);
      acc[ct] = __builtin_amdgcn_mfma_f32_16x16x32_bf16(af, bfr, acc[ct], 0, 0, 0);
    }
  }

  int rowbase = blockIdx.x * 64 + w * 16;
#pragma unroll
  for (int ct = 0; ct < 12; ++ct) {
    int mat = ct >> 2, sub = ct & 3;
    int col = sub * 16 + mi;                  // D col = lane&15
    const float* bp = (mat == 0) ? bq : (mat == 1) ? bk : bv;
    float bias = bp[col];
#pragma unroll
    for (int r = 0; r < 4; ++r) {
      int orow = rowbase + 4 * g + r;         // D row = 4*(lane>>4)+r
      short ov = f2bf(acc[ct][r] + bias);
      if (mat == 0)      Qb[(size_t)orow * HD + col] = ov;
      else if (mat == 1) Kb[(size_t)orow * HD + col] = ov;
      else {
        int b = orow >> 12, s = orow & (SEQ - 1);
        Vt[((size_t)(b * HD + col)) * SEQ + s] = ov;
      }
    }
  }
}

// ---------------------------------------------------------------------------
// Flash attention, swapped layout (S^T = K*Q^T, O^T = V^T*P^T).
// Block = 4 waves, processes q-tile pair (t, 255-t) per batch: uniform work.
// Waves split the kv range 4 ways; merged via LDS flash-combine.
// ---------------------------------------------------------------------------
__global__ __launch_bounds__(256, 2) void attn_kernel(
    const short* __restrict__ Qb, const short* __restrict__ Kb,
    const short* __restrict__ Vt, float* __restrict__ out) {
  __shared__ float lds_o[4][64][16];   // [wave][h][q]
  __shared__ float lds_m[4][16];
  __shared__ float lds_l[4][16];
  __shared__ short p_lds[4][16][32];   // [wave][q][kv]

  int tid  = threadIdx.x;
  int w    = tid >> 6;
  int lane = tid & 63;
  int g    = lane >> 4;
  int qi   = lane & 15;
  int batch = blockIdx.x >> 7;
  int jj    = blockIdx.x & 127;

  for (int ph = 0; ph < 2; ++ph) {
    int t  = ph ? (255 - jj) : jj;
    int q0 = t * 16;
    int row = q0 + qi;                 // this lane's q row (within batch)

    const short* qptr = Qb + ((size_t)(batch * SEQ + row)) * HD + 8 * g;
    bf16x8 qf0 = *(const bf16x8*)(qptr);
    bf16x8 qf1 = *(const bf16x8*)(qptr + 32);

    int C  = t + 1;                    // 16-chunks of kv this tile needs
    int c0 = (w * C) >> 2;
    int c1 = ((w + 1) * C) >> 2;

    float m = -INFINITY, lsum = 0.f;
    f32x4 o[4];
#pragma unroll
    for (int i = 0; i < 4; ++i) o[i] = (f32x4){0.f, 0.f, 0.f, 0.f};

    for (int c = c0; c < c1; c += 2) {
      int kv0 = c * 16;
      bool have1 = (c + 1 < c1);
      float s[2][4];
      {
        const short* kptr = Kb + ((size_t)(batch * SEQ + kv0 + qi)) * HD + 8 * g;
        bf16x8 kf0 = *(const bf16x8*)(kptr);
        bf16x8 kf1 = *(const bf16x8*)(kptr + 32);
        f32x4 z = (f32x4){0.f, 0.f, 0.f, 0.f};
        z = __builtin_amdgcn_mfma_f32_16x16x32_bf16(kf0, qf0, z, 0, 0, 0);
        z = __builtin_amdgcn_mfma_f32_16x16x32_bf16(kf1, qf1, z, 0, 0, 0);
#pragma unroll
        for (int r = 0; r < 4; ++r) {
          int col = kv0 + 4 * g + r;
          s[0][r] = (col <= row) ? z[r] * 0.125f : -INFINITY;
        }
      }
      if (have1) {
        const short* kptr = Kb + ((size_t)(batch * SEQ + kv0 + 16 + qi)) * HD + 8 * g;
        bf16x8 kf0 = *(const bf16x8*)(kptr);
        bf16x8 kf1 = *(const bf16x8*)(kptr + 32);
        f32x4 z = (f32x4){0.f, 0.f, 0.f, 0.f};
        z = __builtin_amdgcn_mfma_f32_16x16x32_bf16(kf0, qf0, z, 0, 0, 0);
        z = __builtin_amdgcn_mfma_f32_16x16x32_bf16(kf1, qf1, z, 0, 0, 0);
#pragma unroll
        for (int r = 0; r < 4; ++r) {
          int col = kv0 + 16 + 4 * g + r;
          s[1][r] = (col <= row) ? z[r] * 0.125f : -INFINITY;
        }
      } else {
#pragma unroll
        for (int r = 0; r < 4; ++r) s[1][r] = -INFINITY;
      }

      float pmax = fmaxf(fmaxf(fmaxf(s[0][0], s[0][1]), fmaxf(s[0][2], s[0][3])),
                         fmaxf(fmaxf(s[1][0], s[1][1]), fmaxf(s[1][2], s[1][3])));
      pmax = fmaxf(pmax, __shfl_xor(pmax, 16));
      pmax = fmaxf(pmax, __shfl_xor(pmax, 32));
      float mnew  = fmaxf(m, pmax);
      float alpha = exp2f((m - mnew) * LOG2E);

      float sum = 0.f;
      unsigned pw[2][2];
#pragma unroll
      for (int f = 0; f < 2; ++f) {
        float p0 = exp2f((s[f][0] - mnew) * LOG2E);
        float p1 = exp2f((s[f][1] - mnew) * LOG2E);
        float p2 = exp2f((s[f][2] - mnew) * LOG2E);
        float p3 = exp2f((s[f][3] - mnew) * LOG2E);
        sum += p0 + p1 + p2 + p3;
        pw[f][0] = ((unsigned)(unsigned short)f2bf(p1) << 16) | (unsigned short)f2bf(p0);
        pw[f][1] = ((unsigned)(unsigned short)f2bf(p3) << 16) | (unsigned short)f2bf(p2);
      }
      sum += __shfl_xor(sum, 16);
      sum += __shfl_xor(sum, 32);
      lsum = lsum * alpha + sum;
      m = mnew;
#pragma unroll
      for (int i = 0; i < 4; ++i) {
        o[i][0] *= alpha; o[i][1] *= alpha; o[i][2] *= alpha; o[i][3] *= alpha;
      }

      // P^T -> LDS (bf16), layout [q][kv32]
      *(uint2*)(&p_lds[w][qi][4 * g])      = make_uint2(pw[0][0], pw[0][1]);
      *(uint2*)(&p_lds[w][qi][16 + 4 * g]) = make_uint2(pw[1][0], pw[1][1]);

      // PV: O^T += V^T * P^T
      bf16x8 pf = *(const bf16x8*)(&p_lds[w][qi][8 * g]);
#pragma unroll
      for (int ht = 0; ht < 4; ++ht) {
        const short* vptr = Vt + ((size_t)(batch * HD + ht * 16 + qi)) * SEQ + kv0 + 8 * g;
        bf16x8 vf = *(const bf16x8*)(vptr);
        o[ht] = __builtin_amdgcn_mfma_f32_16x16x32_bf16(vf, pf, o[ht], 0, 0, 0);
      }
    }

    // per-wave partials -> LDS
#pragma unroll
    for (int ht = 0; ht < 4; ++ht)
#pragma unroll
      for (int r = 0; r < 4; ++r)
        lds_o[w][ht * 16 + 4 * g + r][qi] = o[ht][r];
    if (lane < 16) { lds_m[w][lane] = m; lds_l[w][lane] = lsum; }
    __syncthreads();

    // flash-combine 4 waves, write fp32 output
    {
      int q  = tid & 15;
      int hb = (tid >> 4) * 4;
      float m0 = lds_m[0][q], m1 = lds_m[1][q], m2 = lds_m[2][q], m3 = lds_m[3][q];
      float mm = fmaxf(fmaxf(m0, m1), fmaxf(m2, m3));
      float e0 = exp2f((m0 - mm) * LOG2E);
      float e1 = exp2f((m1 - mm) * LOG2E);
      float e2 = exp2f((m2 - mm) * LOG2E);
      float e3 = exp2f((m3 - mm) * LOG2E);
      float denom = lds_l[0][q] * e0 + lds_l[1][q] * e1 + lds_l[2][q] * e2 + lds_l[3][q] * e3;
      float inv = 1.f / denom;
      f32x4 res;
#pragma unroll
      for (int i = 0; i < 4; ++i) {
        res[i] = (e0 * lds_o[0][hb + i][q] + e1 * lds_o[1][hb + i][q] +
                  e2 * lds_o[2][hb + i][q] + e3 * lds_o[3][hb + i][q]) * inv;
      }
      *(f32x4*)(out + ((size_t)(batch * SEQ + q0 + q)) * HD + hb) = res;
    }
    __syncthreads();
  }
}

// ---------------------------------------------------------------------------
extern "C" void kernel_launch(void* const* d_in, const int* in_sizes, int n_in,
                              void* d_out, int out_size, void* d_ws, size_t ws_size,
                              hipStream_t stream) {
  const float* X  = (const float*)d_in[0];
  const float* Wq = (const float*)d_in[1];
  const float* bq = (const float*)d_in[2];
  const float* Wk = (const float*)d_in[3];
  const float* bk = (const float*)d_in[4];
  const float* Wv = (const float*)d_in[5];
  const float* bv = (const float*)d_in[6];
  float* out = (float*)d_out;

  char* ws = (char*)d_ws;
  const size_t SZ = (size_t)NROW * HD * 2;   // 2 MB per tensor (bf16)
  short* Qb = (short*)(ws);
  short* Kb = (short*)(ws + SZ);
  short* Vt = (short*)(ws + 2 * SZ);
  short* Wt = (short*)(ws + 3 * SZ);         // 384 KB

  wt_kernel<<<192, 256, 0, stream>>>(Wq, Wk, Wv, Wt);
  qkv_kernel<<<NROW / 64, 256, 0, stream>>>(X, Wt, bq, bk, bv, Qb, Kb, Vt);
  attn_kernel<<<BATCH * 128, 256, 0, stream>>>(Qb, Kb, Vt, out);
}